// Round 13
// baseline (595.138 us; speedup 1.0000x reference)
//
#include <hip/hip_runtime.h>

#define NROWS 8192
#define HALF  4096
#define DIM   256
#define JS    16                 // j-splits across grid
#define JRANGE 512               // columns per block
#define JTILES 32                // 16-row j-tiles per block
#define IPB   256                // i rows per block (4 waves x 64)
#define IPW   64                 // i rows per wave

typedef short bf16x8 __attribute__((ext_vector_type(8)));
typedef float f32x4  __attribute__((ext_vector_type(4)));

// async global->LDS, 16B per lane; LDS dest = wave-uniform base + lane*16
#define GLOAD16(g, l) __builtin_amdgcn_global_load_lds( \
    (const __attribute__((address_space(1))) unsigned int*)(g), \
    (__attribute__((address_space(3))) unsigned int*)(l), 16, 0, 0)

__device__ __forceinline__ unsigned short f2bf(float f) {
    unsigned int u = __float_as_uint(f);
    u += 0x7FFFu + ((u >> 16) & 1u);          // round-to-nearest-even
    return (unsigned short)(u >> 16);
}

// --- prep: zb = bf16(sqrt(2)*z) (MFMA then yields sim units directly),
//     exact fp32 positive dots, out = 0 ---
__global__ void k_prep(const float* __restrict__ z1, const float* __restrict__ z2,
                       unsigned short* __restrict__ zb, float* __restrict__ pos,
                       float* __restrict__ out) {
    if (blockIdx.x == 0 && threadIdx.x == 0) *out = 0.0f;
    const float R2 = 1.41421356237309515f;     // sqrt(2): (R2*z)·(R2*z) = 2*z·z = sim
    int w = threadIdx.x >> 6, lane = threadIdx.x & 63;
    int row = blockIdx.x * 4 + w;              // 0 .. 4095
    float4 a = *(const float4*)(z1 + (size_t)row * DIM + lane * 4);
    float4 b = *(const float4*)(z2 + (size_t)row * DIM + lane * 4);

    uint2 pa, pb;
    pa.x = (unsigned int)f2bf(a.x*R2) | ((unsigned int)f2bf(a.y*R2) << 16);
    pa.y = (unsigned int)f2bf(a.z*R2) | ((unsigned int)f2bf(a.w*R2) << 16);
    pb.x = (unsigned int)f2bf(b.x*R2) | ((unsigned int)f2bf(b.y*R2) << 16);
    pb.y = (unsigned int)f2bf(b.z*R2) | ((unsigned int)f2bf(b.w*R2) << 16);
    *(uint2*)(zb + (size_t)row * DIM + lane * 4)          = pa;
    *(uint2*)(zb + (size_t)(row + HALF) * DIM + lane * 4) = pb;

    float d = a.x * b.x + a.y * b.y + a.z * b.z + a.w * b.w;
    #pragma unroll
    for (int k = 32; k; k >>= 1) d += __shfl_xor(d, k);
    if (lane == 0) pos[row] = 2.0f * d;        // exact fp32, sim units
}

// ---------------- main: MFMA matmul + online LSE ----------------
// Round-12 accounting of round-9 (best, 43.8us): LDS pipe 58K cyc/CU was the
// most-loaded (MFMA 33K); per-CU LDS read = waves x j-bytes, only cut by more
// i-rows/wave. Round-12 spill (WRITE 79MB) proved 4 waves/SIMD has 0 reg
// headroom. => IPW=64 at 2 waves/SIMD (256 regs): bf[4][8]=128 AGPR + af
// double-buffer 64 VGPR fits. j-stream read straight from GLOBAL (L1/L2-
// resident, 256KB/block, read once) -- NO LDS, NO BARRIERS in the j-loop;
// loads issue one full tile (~260 cyc MFMA) ahead. k-major inner: 4 chains,
// dep distance 4 x 16 cyc >= MFMA latency.
__global__ __launch_bounds__(256, 2)
void k_main(const unsigned short* __restrict__ zb, float2* __restrict__ part) {
    __shared__ __align__(16) char lds[4][8192];  // prologue staging only
    char* ldsflat = &lds[0][0];

    const int tid  = threadIdx.x;
    const int w    = tid >> 6;
    const int lane = tid & 63;
    const int col  = lane & 15;        // i-local / j-row within tile
    const int kg   = lane >> 4;        // k-group
    const int ib   = blockIdx.x & 31;  // 32 i-panels of 256
    const int js   = blockIdx.x >> 5;  // 16 j-splits
    const int iw   = ib * IPB + w * IPW;
    const int jb0  = js * JRANGE;
    const int swz  = (lane & 7) << 4;  // read-side XOR key ((row&7)<<4), row=col
    const int dr   = col - kg * 4;     // acc reg index hitting the diagonal

    const char* zbb = (const char*)zb;

    // ---- i-panel prologue: global -> LDS (async, pre-swizzled) -> registers.
    // LDS-originated bf loads stay register-resident (proven rounds 5-9);
    // bf[4][8] = 128 AGPRs at 2 waves/SIMD.
    bf16x8 bf[4][8];
    {
        int igo[4];
        #pragma unroll
        for (int k = 0; k < 4; ++k) {
            int p = k * 4096 + w * 1024 + lane * 16;
            igo[k] = p ^ (((p >> 9) & 7) << 4);
        }
        #pragma unroll
        for (int p = 0; p < 8; ++p) {              // pass p: rows [32p, 32p+32)
            const char* gib = zbb + (size_t)(ib * IPB + p * 32) * 512;
            #pragma unroll
            for (int k = 0; k < 4; ++k)
                GLOAD16(gib + igo[k], ldsflat + k * 4096 + w * 1024);
            __syncthreads();                        // drains vmcnt -> data in LDS
            if ((p >> 1) == w) {                    // wave w owns passes 2w, 2w+1
                #pragma unroll
                for (int h = 0; h < 2; ++h) {
                    const char* tb = ldsflat + h * 8192;
                    #pragma unroll
                    for (int kk = 0; kk < 8; ++kk)
                        bf[(p & 1) * 2 + h][kk] =
                            *(const bf16x8*)(tb + col * 512 + (((kk << 6) | (kg << 4)) ^ swz));
                }
            }
            __syncthreads();
        }
    }

    float m[4], l[4];
    #pragma unroll
    for (int is = 0; is < 4; ++is) { m[is] = -1e30f; l[is] = 0.0f; }

    const int dt = (iw - jb0) >> 4;    // tile idx of diagonal for subtile 0

    // lane's global af base: row (jb0+col), byte kg*16 within each 64B k-chunk
    const char* pa = zbb + ((size_t)(jb0 + col) << 9) + kg * 16;

#define LOADAF(AF, OFF) do { \
    _Pragma("unroll") \
    for (int kk = 0; kk < 8; ++kk) \
        AF[kk] = *(const bf16x8*)(pa + (OFF) + kk * 64); \
} while (0)

#define MASKD(X) do { \
    _Pragma("unroll") \
    for (int r = 0; r < 4; ++r) if (dr == r) X[r] = -1e30f; \
} while (0)

#define LSE_UPD(X, is_) do { \
    float t0 = fmaxf(fmaxf(X[0], X[1]), fmaxf(X[2], X[3])); \
    if (__any(t0 > m[is_])) { \
        float mn = fmaxf(m[is_], t0); \
        l[is_] *= __expf(m[is_] - mn); \
        m[is_] = mn; \
    } \
    l[is_] += __expf(X[0] - m[is_]) + __expf(X[1] - m[is_]) \
            + __expf(X[2] - m[is_]) + __expf(X[3] - m[is_]); \
} while (0)

// k-major, 4 independent accumulator chains (one per i-subtile):
// dep distance 4 x ~16 cyc/SIMD >= MFMA latency.
#define COMP(AF, T) do { \
    f32x4 a0 = {0.f, 0.f, 0.f, 0.f}; \
    f32x4 a1 = a0, a2 = a0, a3 = a0; \
    _Pragma("unroll") \
    for (int kk = 0; kk < 8; ++kk) { \
        a0 = __builtin_amdgcn_mfma_f32_16x16x32_bf16(AF[kk], bf[0][kk], a0, 0, 0, 0); \
        a1 = __builtin_amdgcn_mfma_f32_16x16x32_bf16(AF[kk], bf[1][kk], a1, 0, 0, 0); \
        a2 = __builtin_amdgcn_mfma_f32_16x16x32_bf16(AF[kk], bf[2][kk], a2, 0, 0, 0); \
        a3 = __builtin_amdgcn_mfma_f32_16x16x32_bf16(AF[kk], bf[3][kk], a3, 0, 0, 0); \
    } \
    const int dd = (T) - dt; \
    if (dd == 0) MASKD(a0); \
    if (dd == 1) MASKD(a1); \
    if (dd == 2) MASKD(a2); \
    if (dd == 3) MASKD(a3); \
    LSE_UPD(a0, 0); \
    LSE_UPD(a1, 1); \
    LSE_UPD(a2, 2); \
    LSE_UPD(a3, 3); \
} while (0)

    bf16x8 af0[8], af1[8];
    LOADAF(af0, 0);                        // tile 0
    #pragma unroll 4
    for (int u = 0; u < JTILES / 2 - 1; ++u) {
        LOADAF(af1, 8192);                 // tile 2u+1, issued a tile ahead
        COMP(af0, 2 * u);
        LOADAF(af0, 16384);                // tile 2u+2
        COMP(af1, 2 * u + 1);
        pa += 16384;
    }
    LOADAF(af1, 8192);                     // last tile
    COMP(af0, JTILES - 2);
    COMP(af1, JTILES - 1);

#undef LOADAF
#undef MASKD
#undef LSE_UPD
#undef COMP

    // merge the 4 kg groups holding the same i (lanes col, +16, +32, +48)
    #pragma unroll
    for (int is = 0; is < 4; ++is) {
        float mm = m[is], ll = l[is];
        #pragma unroll
        for (int msk = 16; msk <= 32; msk <<= 1) {
            float mo  = __shfl_xor(mm, msk);
            float lo_ = __shfl_xor(ll, msk);
            float mn  = fmaxf(mm, mo);
            ll = ll * __expf(mm - mn) + lo_ * __expf(mo - mn);
            mm = mn;
        }
        if (kg == 0) part[(size_t)(iw + is * 16 + col) * JS + js] = make_float2(mm, ll);
    }
}

// ---------------- final: merge partials, loss, reduce ----------------
__global__ void k_final(const float2* __restrict__ part, const float* __restrict__ pos,
                        float* __restrict__ out) {
    int tid = threadIdx.x;
    int i = blockIdx.x * 256 + tid;
    const float2* p = part + (size_t)i * JS;
    float2 v[JS];
    float M = -3e30f;
    #pragma unroll
    for (int s = 0; s < JS; ++s) { v[s] = p[s]; M = fmaxf(M, v[s].x); }
    float L = 0.0f;
    #pragma unroll
    for (int s = 0; s < JS; ++s) L += v[s].y * __expf(v[s].x - M);
    float loss = M + __logf(L) - pos[i & (HALF - 1)];

    #pragma unroll
    for (int k = 32; k; k >>= 1) loss += __shfl_down(loss, k);
    __shared__ float ps[4];
    int w = tid >> 6, lane = tid & 63;
    if (lane == 0) ps[w] = loss;
    __syncthreads();
    if (tid == 0) atomicAdd(out, (ps[0] + ps[1] + ps[2] + ps[3]) * (1.0f / (float)NROWS));
}

extern "C" void kernel_launch(void* const* d_in, const int* in_sizes, int n_in,
                              void* d_out, int out_size, void* d_ws, size_t ws_size,
                              hipStream_t stream) {
    const float* z1 = (const float*)d_in[0];
    const float* z2 = (const float*)d_in[1];
    float* out = (float*)d_out;

    char* ws = (char*)d_ws;
    unsigned short* zb = (unsigned short*)ws;                          // 4 MiB
    float* pos  = (float*)(ws + 4u * 1024u * 1024u);                   // 16 KiB
    float2* part = (float2*)(ws + 4u * 1024u * 1024u + 65536u);        // 1 MiB

    k_prep <<<1024, 256, 0, stream>>>(z1, z2, zb, pos, out);
    k_main <<<512,  256, 0, stream>>>(zb, part);
    k_final<<<32,   256, 0, stream>>>(part, pos, out);
}

// Round 14
// 182.699 us; speedup vs baseline: 3.2575x; 3.2575x over previous
//
#include <hip/hip_runtime.h>

#define NROWS 8192
#define HALF  4096
#define DIM   256
#define JS    16                 // j-splits across grid
#define JRANGE 512               // columns per block
#define JTILES 32                // 16-row j-tiles per block
#define IPB   128                // i rows per block (4 waves x 32)
#define IPW   32                 // i rows per wave

typedef short bf16x8 __attribute__((ext_vector_type(8)));
typedef float f32x4  __attribute__((ext_vector_type(4)));

// async global->LDS, 16B per lane; LDS dest = wave-uniform base + lane*16
#define GLOAD16(g, l) __builtin_amdgcn_global_load_lds( \
    (const __attribute__((address_space(1))) unsigned int*)(g), \
    (__attribute__((address_space(3))) unsigned int*)(l), 16, 0, 0)

__device__ __forceinline__ unsigned short f2bf(float f) {
    unsigned int u = __float_as_uint(f);
    u += 0x7FFFu + ((u >> 16) & 1u);          // round-to-nearest-even
    return (unsigned short)(u >> 16);
}

// --- prep: zb = bf16(sqrt(2)*z) (MFMA then yields sim units directly),
//     exact fp32 positive dots, out = 0 ---
__global__ void k_prep(const float* __restrict__ z1, const float* __restrict__ z2,
                       unsigned short* __restrict__ zb, float* __restrict__ pos,
                       float* __restrict__ out) {
    if (blockIdx.x == 0 && threadIdx.x == 0) *out = 0.0f;
    const float R2 = 1.41421356237309515f;     // sqrt(2): (R2*z)·(R2*z) = 2*z·z = sim
    int w = threadIdx.x >> 6, lane = threadIdx.x & 63;
    int row = blockIdx.x * 4 + w;              // 0 .. 4095
    float4 a = *(const float4*)(z1 + (size_t)row * DIM + lane * 4);
    float4 b = *(const float4*)(z2 + (size_t)row * DIM + lane * 4);

    uint2 pa, pb;
    pa.x = (unsigned int)f2bf(a.x*R2) | ((unsigned int)f2bf(a.y*R2) << 16);
    pa.y = (unsigned int)f2bf(a.z*R2) | ((unsigned int)f2bf(a.w*R2) << 16);
    pb.x = (unsigned int)f2bf(b.x*R2) | ((unsigned int)f2bf(b.y*R2) << 16);
    pb.y = (unsigned int)f2bf(b.z*R2) | ((unsigned int)f2bf(b.w*R2) << 16);
    *(uint2*)(zb + (size_t)row * DIM + lane * 4)          = pa;
    *(uint2*)(zb + (size_t)(row + HALF) * DIM + lane * 4) = pb;

    float d = a.x * b.x + a.y * b.y + a.z * b.z + a.w * b.w;
    #pragma unroll
    for (int k = 32; k; k >>= 1) d += __shfl_xor(d, k);
    if (lane == 0) pos[row] = 2.0f * d;        // exact fp32, sim units
}

// ---------------- main: MFMA matmul + online LSE ----------------
// EXACT round-9 kernel (proven 43.8us) with ONE change: the j-loop's two
// __syncthreads (which force s_waitcnt vmcnt(0) lgkmcnt(0) drains) become
// raw s_barrier + hand-counted waits: vmcnt(4) waits only for the OLDER
// staged pair (the just-issued pair stays in flight across the barrier),
// lgkmcnt(0) only before a buffer is overwritten. (T4 counted-vmcnt; m218.)
__global__ __launch_bounds__(256, 4)
void k_main(const unsigned short* __restrict__ zb, float2* __restrict__ part) {
    __shared__ __align__(16) char lds[4][8192];  // 4 static 16-row buffers
    char* ldsflat = &lds[0][0];

    const int tid  = threadIdx.x;
    const int w    = tid >> 6;
    const int lane = tid & 63;
    const int col  = lane & 15;        // i-local / j-row within tile
    const int kg   = lane >> 4;        // k-group
    const int ib   = blockIdx.x & 63;  // 64 i-tiles of 128
    const int js   = blockIdx.x >> 6;  // 16 j-splits
    const int iw   = ib * IPB + w * IPW;
    const int jb0  = js * JRANGE;
    const int swz  = (lane & 7) << 4;  // read-side XOR key ((row&7)<<4), row=col
    const int dr   = col - kg * 4;     // acc reg index hitting the diagonal

    const char* zbb = (const char*)zb;

    // pre-swizzled global source offsets (involution of the LDS XOR swizzle)
    const int jp0 = w * 1024 + lane * 16;          // chunk 0 phys
    const int jp1 = 4096 + jp0;                    // chunk 1 phys
    const int jg0 = jp0 ^ (((jp0 >> 9) & 7) << 4);
    const int jg1 = jp1 ^ (((jp1 >> 9) & 7) << 4);

    // ---- i-panel prologue: global -> LDS (async, pre-swizzled) -> registers ----
    bf16x8 bf[2][8];                   // wave's 32 i-rows (AGPR-resident)
    {
        int igo[4];
        #pragma unroll
        for (int k = 0; k < 4; ++k) {
            int p = k * 4096 + w * 1024 + lane * 16;
            igo[k] = p ^ (((p >> 9) & 7) << 4);
        }
        #pragma unroll
        for (int q = 0; q < 4; ++q) {             // pass q: rows [32q, 32q+32)
            const char* gib = zbb + (size_t)(ib * IPB + q * 32) * 512;
            #pragma unroll
            for (int k = 0; k < 4; ++k)
                GLOAD16(gib + igo[k], ldsflat + k * 4096 + w * 1024);
            __syncthreads();                      // drains vmcnt -> data in LDS
            if (q == w) {                         // wave w owns pass w
                #pragma unroll
                for (int h = 0; h < 2; ++h) {
                    const char* tb = ldsflat + h * 8192;
                    #pragma unroll
                    for (int kk = 0; kk < 8; ++kk)
                        bf[h][kk] =
                            *(const bf16x8*)(tb + col * 512 + (((kk << 6) | (kg << 4)) ^ swz));
                }
            }
            __syncthreads();
        }
    }

    float m0 = -1e30f, m1 = -1e30f, l0 = 0.0f, l1 = 0.0f;

    // static af addressing: one base + per-kk lane consts + buffer imm offsets
    const char* ap = ldsflat + col * 512;
    int aoff[8];
    #pragma unroll
    for (int kk = 0; kk < 8; ++kk) aoff[kk] = ((kk << 6) | (kg << 4)) ^ swz;

    const int dt = (iw - jb0) >> 4;                // tile idx of diagonal, subtile 0
    const char* jbase = zbb + (size_t)jb0 * 512;

#define JSTAGE(T, B) do { \
    GLOAD16(jbase + (size_t)(T) * 8192 + jg0, ldsflat + (B) * 8192 + w * 1024); \
    GLOAD16(jbase + (size_t)(T) * 8192 + jg1, ldsflat + (B) * 8192 + 4096 + w * 1024); \
} while (0)

#define MASKD(X) do { \
    _Pragma("unroll") \
    for (int r = 0; r < 4; ++r) if (dr == r) X[r] = -1e30f; \
} while (0)

#define LSE0(X) do { \
    float t0 = fmaxf(fmaxf(X[0], X[1]), fmaxf(X[2], X[3])); \
    if (__any(t0 > m0)) { \
        float mn = fmaxf(m0, t0); \
        l0 *= __expf(m0 - mn); \
        m0 = mn; \
    } \
    l0 += __expf(X[0] - m0) + __expf(X[1] - m0) \
        + __expf(X[2] - m0) + __expf(X[3] - m0); \
} while (0)

#define LSE1(X) do { \
    float t0 = fmaxf(fmaxf(X[0], X[1]), fmaxf(X[2], X[3])); \
    if (__any(t0 > m1)) { \
        float mn = fmaxf(m1, t0); \
        l1 *= __expf(m1 - mn); \
        m1 = mn; \
    } \
    l1 += __expf(X[0] - m1) + __expf(X[1] - m1) \
        + __expf(X[2] - m1) + __expf(X[3] - m1); \
} while (0)

#define COMPUTE_TILE(B, T) do { \
    f32x4 a0 = {0.f, 0.f, 0.f, 0.f}; \
    f32x4 a1 = a0; \
    bf16x8 af[4]; \
    _Pragma("unroll") \
    for (int kk = 0; kk < 4; ++kk) \
        af[kk] = *(const bf16x8*)(ap + aoff[kk] + (B) * 8192); \
    _Pragma("unroll") \
    for (int kk = 0; kk < 4; ++kk) { \
        a0 = __builtin_amdgcn_mfma_f32_16x16x32_bf16(af[kk], bf[0][kk], a0, 0, 0, 0); \
        a1 = __builtin_amdgcn_mfma_f32_16x16x32_bf16(af[kk], bf[1][kk], a1, 0, 0, 0); \
    } \
    _Pragma("unroll") \
    for (int kk = 0; kk < 4; ++kk) \
        af[kk] = *(const bf16x8*)(ap + aoff[kk + 4] + (B) * 8192); \
    _Pragma("unroll") \
    for (int kk = 0; kk < 4; ++kk) { \
        a0 = __builtin_amdgcn_mfma_f32_16x16x32_bf16(af[kk], bf[0][kk + 4], a0, 0, 0, 0); \
        a1 = __builtin_amdgcn_mfma_f32_16x16x32_bf16(af[kk], bf[1][kk + 4], a1, 0, 0, 0); \
    } \
    const int dd = (T) - dt; \
    if (dd == 0) MASKD(a0); \
    if (dd == 1) MASKD(a1); \
    LSE0(a0); \
    LSE1(a1); \
} while (0)

    // prologue: tiles 0,1 -> L0,L1 (wait happens at first in-loop vmcnt(4))
    JSTAGE(0, 0); JSTAGE(1, 1);

    for (int u = 0; u < JTILES / 4; ++u) {
        const int t = u * 4;
        // stage next pair early; wait only for the OLDER pair (counted vmcnt)
        JSTAGE(t + 2, 2); JSTAGE(t + 3, 3);
        asm volatile("s_waitcnt vmcnt(4)" ::: "memory");   // L0,L1 data landed
        __builtin_amdgcn_s_barrier();
        COMPUTE_TILE(0, t);
        COMPUTE_TILE(1, t + 1);
        asm volatile("s_waitcnt lgkmcnt(0)" ::: "memory"); // my L0,L1 reads done
        __builtin_amdgcn_s_barrier();                      // all waves done w/ L0,L1
        if (u < JTILES / 4 - 1) {
            JSTAGE(t + 4, 0); JSTAGE(t + 5, 1);
            asm volatile("s_waitcnt vmcnt(4)" ::: "memory"); // L2,L3 data landed
        } else {
            asm volatile("s_waitcnt vmcnt(0)" ::: "memory"); // drain tail
        }
        __builtin_amdgcn_s_barrier();
        COMPUTE_TILE(2, t + 2);
        COMPUTE_TILE(3, t + 3);
        asm volatile("s_waitcnt lgkmcnt(0)" ::: "memory");
        __builtin_amdgcn_s_barrier();
    }

    // merge the 4 kg groups holding the same i
    {
        float mm = m0, ll = l0;
        #pragma unroll
        for (int msk = 16; msk <= 32; msk <<= 1) {
            float mo  = __shfl_xor(mm, msk);
            float lo_ = __shfl_xor(ll, msk);
            float mn  = fmaxf(mm, mo);
            ll = ll * __expf(mm - mn) + lo_ * __expf(mo - mn);
            mm = mn;
        }
        if (kg == 0) part[(size_t)(iw + col) * JS + js] = make_float2(mm, ll);
    }
    {
        float mm = m1, ll = l1;
        #pragma unroll
        for (int msk = 16; msk <= 32; msk <<= 1) {
            float mo  = __shfl_xor(mm, msk);
            float lo_ = __shfl_xor(ll, msk);
            float mn  = fmaxf(mm, mo);
            ll = ll * __expf(mm - mn) + lo_ * __expf(mo - mn);
            mm = mn;
        }
        if (kg == 0) part[(size_t)(iw + 16 + col) * JS + js] = make_float2(mm, ll);
    }
#undef JSTAGE
#undef MASKD
#undef LSE0
#undef LSE1
#undef COMPUTE_TILE
}

// ---------------- final: merge partials, loss, reduce ----------------
__global__ void k_final(const float2* __restrict__ part, const float* __restrict__ pos,
                        float* __restrict__ out) {
    int tid = threadIdx.x;
    int i = blockIdx.x * 256 + tid;
    const float2* p = part + (size_t)i * JS;
    float2 v[JS];
    float M = -3e30f;
    #pragma unroll
    for (int s = 0; s < JS; ++s) { v[s] = p[s]; M = fmaxf(M, v[s].x); }
    float L = 0.0f;
    #pragma unroll
    for (int s = 0; s < JS; ++s) L += v[s].y * __expf(v[s].x - M);
    float loss = M + __logf(L) - pos[i & (HALF - 1)];

    #pragma unroll
    for (int k = 32; k; k >>= 1) loss += __shfl_down(loss, k);
    __shared__ float ps[4];
    int w = tid >> 6, lane = tid & 63;
    if (lane == 0) ps[w] = loss;
    __syncthreads();
    if (tid == 0) atomicAdd(out, (ps[0] + ps[1] + ps[2] + ps[3]) * (1.0f / (float)NROWS));
}

extern "C" void kernel_launch(void* const* d_in, const int* in_sizes, int n_in,
                              void* d_out, int out_size, void* d_ws, size_t ws_size,
                              hipStream_t stream) {
    const float* z1 = (const float*)d_in[0];
    const float* z2 = (const float*)d_in[1];
    float* out = (float*)d_out;

    char* ws = (char*)d_ws;
    unsigned short* zb = (unsigned short*)ws;                          // 4 MiB
    float* pos  = (float*)(ws + 4u * 1024u * 1024u);                   // 16 KiB
    float2* part = (float2*)(ws + 4u * 1024u * 1024u + 65536u);        // 1 MiB

    k_prep <<<1024, 256, 0, stream>>>(z1, z2, zb, pos, out);
    k_main <<<1024, 256, 0, stream>>>(zb, part);
    k_final<<<32,   256, 0, stream>>>(part, pos, out);
}